// Round 8
// baseline (1818.408 us; speedup 1.0000x reference)
//
#include <hip/hip_runtime.h>
#include <math.h>

#define NN 50000
#define MP 50048          // NN padded to multiple of 128 (32 rows x 4 waves)
#define NE 800000
#define FIN 64
#define HD 200
#define NG 256
#define SCAN_B 256
#define KP2 256           // padded row: 8 slots x 32 halfs (64 B each), 28 real cols/slot
#define NT 13             // 13 * 16 = 208 >= 200 output col tiles

typedef _Float16 h16;
typedef __attribute__((ext_vector_type(8))) _Float16 half8;
typedef __attribute__((ext_vector_type(4))) float float4v;

// ---------- setup: src out-degree (float) + dst in-degree (int, for CSR) ----------
__global__ void k_deg(const int* __restrict__ src, const int* __restrict__ dst,
                      float* __restrict__ deg, int* __restrict__ cnt_dst, int E) {
    int e = blockIdx.x * blockDim.x + threadIdx.x;
    if (e < E) {
        atomicAdd(&deg[src[e]], 1.0f);
        atomicAdd(&cnt_dst[dst[e]], 1);
    }
}

__global__ void k_node_prep(float* __restrict__ degdis, const int* __restrict__ batch,
                            const float* __restrict__ lmax, float* __restrict__ diag, int n) {
    int i = blockIdx.x * blockDim.x + threadIdx.x;
    if (i < n) {
        float d = degdis[i];
        degdis[i] = (d > 0.f) ? (1.0f / sqrtf(fmaxf(d, 1.0f))) : 0.0f;   // dis
        diag[i] = 2.0f / lmax[batch[i]] - 1.0f;
    }
}

// ---------- exclusive scan over cnt_dst ----------
__global__ void k_scan1(const int* __restrict__ cnt, int* __restrict__ excl,
                        int* __restrict__ bsum, int n) {
    __shared__ int sh[SCAN_B];
    int tid = threadIdx.x;
    int i = blockIdx.x * SCAN_B + tid;
    int v = (i < n) ? cnt[i] : 0;
    sh[tid] = v;
    __syncthreads();
    for (int off = 1; off < SCAN_B; off <<= 1) {
        int t = (tid >= off) ? sh[tid - off] : 0;
        __syncthreads();
        sh[tid] += t;
        __syncthreads();
    }
    if (i < n) excl[i] = sh[tid] - v;
    if (tid == SCAN_B - 1) bsum[blockIdx.x] = sh[tid];
}

__global__ void k_scan2(int* __restrict__ bsum, int nb) {
    __shared__ int sh[SCAN_B];
    int tid = threadIdx.x;
    int v = (tid < nb) ? bsum[tid] : 0;
    sh[tid] = v;
    __syncthreads();
    for (int off = 1; off < SCAN_B; off <<= 1) {
        int t = (tid >= off) ? sh[tid - off] : 0;
        __syncthreads();
        sh[tid] += t;
        __syncthreads();
    }
    if (tid < nb) bsum[tid] = sh[tid] - v;   // exclusive
}

__global__ void k_scan3(int* __restrict__ excl, const int* __restrict__ bsum, int n) {
    int i = blockIdx.x * SCAN_B + threadIdx.x;
    if (i < n) excl[i] += bsum[blockIdx.x];
}

// ---------- permute edges into CSR-by-dst order, packed {src, w} in one u64 ----------
__global__ void k_fillcsr(const int* __restrict__ src, const int* __restrict__ dst,
                          const int* __restrict__ batch, const float* __restrict__ lmax,
                          const float* __restrict__ dis, const int* __restrict__ rowstart,
                          int* __restrict__ fill, unsigned long long* __restrict__ csr, int E) {
    int e = blockIdx.x * blockDim.x + threadIdx.x;
    if (e < E) {
        int s = src[e], d = dst[e];
        int pos = rowstart[d] + atomicAdd(&fill[d], 1);
        float w = -dis[s] * dis[d] * (2.0f / lmax[batch[s]]);
        unsigned long long packed = (unsigned)s |
            ((unsigned long long)__float_as_uint(w) << 32);
        csr[pos] = packed;
    }
}

// ---------- fp32 -> fp16 split for x ----------
__global__ void k_split(const float* __restrict__ x, h16* __restrict__ x16, int total) {
    int i = blockIdx.x * blockDim.x + threadIdx.x;
    if (i < total) x16[i] = (h16)x[i];
}

// ---------- W pre-transpose: f32 [3][fin][HD] -> fp16 [seg][ks][208][32] ----------
// padded=1: k-slot ks holds real k = ks*28 + kk (kk<28), zeros at pads (matches KP2 layout)
__global__ void k_wprep(const float* __restrict__ W, h16* __restrict__ out,
                        int fin, int ksteps, int padded, int total) {
    int idx = blockIdx.x * blockDim.x + threadIdx.x;
    if (idx >= total) return;
    int kk = idx & 31;
    int r = idx >> 5;
    int nn = r % 208;
    int r2 = r / 208;
    int ks = r2 % ksteps;
    int seg = r2 / ksteps;
    int kreal; bool valid;
    if (padded) { kreal = ks * 28 + kk; valid = (kk < 28) && (kreal < fin); }
    else        { kreal = ks * 32 + kk; valid = (kreal < fin); }
    out[idx] = (nn < HD && valid) ? (h16)W[((size_t)seg * fin + kreal) * HD + nn] : (h16)0.f;
}

// ---------- graph boundaries (batch is sorted) ----------
__global__ void k_bounds(const int* __restrict__ batch, int* __restrict__ gstart, int n) {
    int g = blockIdx.x * blockDim.x + threadIdx.x;
    if (g > NG) return;
    if (g == NG) { gstart[NG] = n; return; }
    int lo = 0, hi = n;
    while (lo < hi) {
        int mid = (lo + hi) >> 1;
        if (batch[mid] < g) lo = mid + 1; else hi = mid;
    }
    gstart[g] = lo;
}

// ---------- propagation (gather, fp16, 64B-aligned XCD-pinned column chunks) ----------
// chunk = blockIdx.x % nch: with round-robin block->XCD dispatch, each XCD sees one
// chunk only -> per-XCD h-footprint = 50048 x 64 B = 3.2 MB < 4 MB L2.
// CSR u64 pairs streamed with non-temporal loads (no L2 pollution).
// 8-lane group per node (8 x 8 B = one 64 B chunk), 32 nodes per 256-thr block.
// mode 0: v = gath + diag*hin        mode 1: v = 2*(gath + diag*hin) - hin0
__global__ __launch_bounds__(256) void k_gather(
    const int* __restrict__ rowstart, const int* __restrict__ rowcnt,
    const unsigned long long* __restrict__ csr, const float* __restrict__ diag,
    const h16* __restrict__ hin16, const h16* __restrict__ h016,
    h16* __restrict__ hout16, int s16, int nch, int n, int mode) {
    int chunk = blockIdx.x % nch;
    int nb = blockIdx.x / nch;
    int i = nb * 32 + (threadIdx.x >> 3);
    if (i >= n) return;
    int gl = threadIdx.x & 7;
    int c0 = chunk * 32 + gl * 4;                  // 8-byte aligned, inside one 64B sector
    int start = rowstart[i], cnt = rowcnt[i];
    float a0 = 0.f, a1 = 0.f, a2 = 0.f, a3 = 0.f;
    union U { uint2 u; h16 h[4]; };
    const unsigned long long* cp = csr + start;
    int k = 0;
    for (; k + 1 < cnt; k += 2) {
        unsigned long long e0 = __builtin_nontemporal_load(cp + k);
        unsigned long long e1 = __builtin_nontemporal_load(cp + k + 1);
        int s0 = (int)(unsigned)e0, s1 = (int)(unsigned)e1;
        float w0 = __uint_as_float((unsigned)(e0 >> 32));
        float w1 = __uint_as_float((unsigned)(e1 >> 32));
        U p0, p1;
        p0.u = *(const uint2*)(hin16 + (size_t)s0 * s16 + c0);
        p1.u = *(const uint2*)(hin16 + (size_t)s1 * s16 + c0);
        a0 += w0 * (float)p0.h[0] + w1 * (float)p1.h[0];
        a1 += w0 * (float)p0.h[1] + w1 * (float)p1.h[1];
        a2 += w0 * (float)p0.h[2] + w1 * (float)p1.h[2];
        a3 += w0 * (float)p0.h[3] + w1 * (float)p1.h[3];
    }
    if (k < cnt) {
        unsigned long long e0 = __builtin_nontemporal_load(cp + k);
        int s0 = (int)(unsigned)e0;
        float w0 = __uint_as_float((unsigned)(e0 >> 32));
        U p0;
        p0.u = *(const uint2*)(hin16 + (size_t)s0 * s16 + c0);
        a0 += w0 * (float)p0.h[0];
        a1 += w0 * (float)p0.h[1];
        a2 += w0 * (float)p0.h[2];
        a3 += w0 * (float)p0.h[3];
    }
    float dg = diag[i];
    U hs; hs.u = *(const uint2*)(hin16 + (size_t)i * s16 + c0);
    float v0 = a0 + dg * (float)hs.h[0];
    float v1 = a1 + dg * (float)hs.h[1];
    float v2 = a2 + dg * (float)hs.h[2];
    float v3 = a3 + dg * (float)hs.h[3];
    if (mode == 1) {
        U h0; h0.u = *(const uint2*)(h016 + (size_t)i * s16 + c0);
        v0 = 2.f * v0 - (float)h0.h[0];
        v1 = 2.f * v1 - (float)h0.h[1];
        v2 = 2.f * v2 - (float)h0.h[2];
        v3 = 2.f * v3 - (float)h0.h[3];
    }
    U o;
    o.h[0] = (h16)v0; o.h[1] = (h16)v1; o.h[2] = (h16)v2; o.h[3] = (h16)v3;
    *(uint2*)(hout16 + (size_t)i * s16 + c0) = o.u;
}

// ---------- MFMA fp16 GEMM, barrier-free: out = relu([A0|A1|A2] @ W + b) ----------
// Each wave: 32 rows x 208 cols. A rows use the slot layout (k-step == 64B slot).
__global__ __launch_bounds__(256) void k_gemm16(
    const h16* __restrict__ A0, const h16* __restrict__ A1, const h16* __restrict__ A2,
    int strideA, int ksteps, int padded,
    const h16* __restrict__ Wt, const float* __restrict__ bias,
    float* __restrict__ outF, h16* __restrict__ out16, int n) {
    int tid = threadIdx.x;
    int wave = tid >> 6, lane = tid & 63;
    int nq = lane & 15, quad = lane >> 4;
    int row0 = (blockIdx.x * 4 + wave) * 32;
    const h16* Aseg[3] = {A0, A1, A2};

    float4v acc[2][NT];
#pragma unroll
    for (int r = 0; r < 2; r++)
#pragma unroll
        for (int t = 0; t < NT; t++) acc[r][t] = (float4v)0.f;

    for (int seg = 0; seg < 3; ++seg) {
        const h16* Ab = Aseg[seg] + (size_t)(row0 + nq) * strideA + quad * 8;
        const h16* Bb = Wt + (size_t)seg * ksteps * 208 * 32 + (size_t)nq * 32 + quad * 8;
        for (int ks = 0; ks < ksteps; ++ks) {
            half8 af0 = *(const half8*)(Ab + ks * 32);
            half8 af1 = *(const half8*)(Ab + 16 * strideA + ks * 32);
            const h16* Bk = Bb + (size_t)ks * 208 * 32;
#pragma unroll
            for (int t = 0; t < NT; ++t) {
                half8 bf = *(const half8*)(Bk + t * 16 * 32);
                acc[0][t] = __builtin_amdgcn_mfma_f32_16x16x32_f16(af0, bf, acc[0][t], 0, 0, 0);
                acc[1][t] = __builtin_amdgcn_mfma_f32_16x16x32_f16(af1, bf, acc[1][t], 0, 0, 0);
            }
        }
    }
#pragma unroll
    for (int r = 0; r < 2; ++r) {
        int rowb = row0 + r * 16 + quad * 4;
#pragma unroll
        for (int t = 0; t < NT; ++t) {
            int col = t * 16 + nq;
            if (col >= HD) continue;
            float bj = bias[col];
            int pcol = (col / 28) * 32 + (col % 28);   // padded-slot position
#pragma unroll
            for (int g = 0; g < 4; ++g) {
                int row = rowb + g;
                if (row < n) {
                    float v = fmaxf(acc[r][t][g] + bj, 0.0f);
                    if (outF)  outF[(size_t)row * HD + col] = v;
                    if (out16) out16[(size_t)row * KP2 + pcol] = (h16)v;
                }
            }
        }
    }
}

// ---------- fused segmented pool (mean+max) + FC + log_softmax: one block per graph ----------
__global__ __launch_bounds__(256) void k_pool_fc(
    const float* __restrict__ Hf, const int* __restrict__ gstart,
    const float* __restrict__ fcw, const float* __restrict__ fcb,
    float* __restrict__ out) {
    __shared__ float red[8];
    int g = blockIdx.x;
    int j = threadIdx.x;
    int i0 = gstart[g], i1 = gstart[g + 1];
    float s0 = 0.f, s1 = 0.f, s2 = 0.f, s3 = 0.f, mx = 0.f;   // post-ReLU: max >= 0
    if (j < HD) {
        int i = i0;
        for (; i + 3 < i1; i += 4) {
            float v0 = Hf[(size_t)i * HD + j];
            float v1 = Hf[(size_t)(i + 1) * HD + j];
            float v2 = Hf[(size_t)(i + 2) * HD + j];
            float v3 = Hf[(size_t)(i + 3) * HD + j];
            s0 += v0; s1 += v1; s2 += v2; s3 += v3;
            mx = fmaxf(mx, fmaxf(fmaxf(v0, v1), fmaxf(v2, v3)));
        }
        for (; i < i1; ++i) {
            float v = Hf[(size_t)i * HD + j];
            s0 += v; mx = fmaxf(mx, v);
        }
    }
    float cntf = (float)(i1 - i0);
    float mean = (s0 + s1 + s2 + s3) / fmaxf(cntf, 1.f);
    float p0 = 0.f, p1 = 0.f;
    if (j < HD) {
        p0 = mean * fcw[2 * j]     + mx * fcw[2 * (HD + j)];
        p1 = mean * fcw[2 * j + 1] + mx * fcw[2 * (HD + j) + 1];
    }
#pragma unroll
    for (int o = 32; o > 0; o >>= 1) {
        p0 += __shfl_down(p0, o);
        p1 += __shfl_down(p1, o);
    }
    int wave = j >> 6, lane = j & 63;
    if (lane == 0) { red[wave * 2] = p0; red[wave * 2 + 1] = p1; }
    __syncthreads();
    if (j == 0) {
        float z0 = red[0] + red[2] + red[4] + red[6] + fcb[0];
        float z1 = red[1] + red[3] + red[5] + red[7] + fcb[1];
        float m = fmaxf(z0, z1);
        float lse = m + logf(expf(z0 - m) + expf(z1 - m));
        out[g * 2 + 0] = z0 - lse;
        out[g * 2 + 1] = z1 - lse;
    }
}

extern "C" void kernel_launch(void* const* d_in, const int* in_sizes, int n_in,
                              void* d_out, int out_size, void* d_ws, size_t ws_size,
                              hipStream_t stream) {
    const float* x     = (const float*)d_in[0];
    const int*   edge  = (const int*)d_in[1];
    const int*   batch = (const int*)d_in[2];
    const float* lmax  = (const float*)d_in[3];
    const float* W1 = (const float*)d_in[4];  const float* b1 = (const float*)d_in[5];
    const float* W2 = (const float*)d_in[6];  const float* b2 = (const float*)d_in[7];
    const float* W3 = (const float*)d_in[8];  const float* b3 = (const float*)d_in[9];
    const float* W4 = (const float*)d_in[10]; const float* b4 = (const float*)d_in[11];
    const float* fcw = (const float*)d_in[12]; const float* fcb = (const float*)d_in[13];
    float* out = (float*)d_out;

    const int n = NN, E = NE;
    const int* src = edge;
    const int* dst = edge + E;

    // workspace layout (float units, each buffer 16B-aligned)
    float* ws = (float*)d_ws;
    size_t off = 0;
    auto alloc = [&](size_t nfloats) { float* p = ws + off; off += (nfloats + 3) & ~(size_t)3; return p; };
    float* dis    = alloc(NN);
    float* diag   = alloc(NN);
    int*   cntd   = (int*)alloc(NN);
    int*   rowst  = (int*)alloc(NN);
    int*   fill   = (int*)alloc(NN);
    int*   bsum   = (int*)alloc(SCAN_B);
    unsigned long long* csr = (unsigned long long*)alloc((size_t)NE * 2);  // packed {src, w}
    int*   gstart = (int*)alloc(NG + 1);
    float* H      = alloc((size_t)MP * HD);               // f32 final-layer features (pool)
    h16*   x16    = (h16*)alloc((size_t)MP * FIN / 2);    // fp16 x (stride 64, 2 slots)
    h16*   hi0    = (h16*)alloc((size_t)MP * KP2 / 2);    // fp16 Tx0 (in-place per layer)
    h16*   hi1    = (h16*)alloc((size_t)MP * KP2 / 2);    // fp16 Tx1
    h16*   hi2    = (h16*)alloc((size_t)MP * KP2 / 2);    // fp16 Tx2
    const int WSZ0 = 3 * 2 * 208 * 32;                    // layer 0 (fin=64, ksteps=2)
    const int WSZ  = 3 * 8 * 208 * 32;                    // layers 1-3 (ksteps=8, padded)
    h16* wt0 = (h16*)alloc(WSZ0 / 2);
    h16* wt1 = (h16*)alloc(WSZ / 2);
    h16* wt2 = (h16*)alloc(WSZ / 2);
    h16* wt3 = (h16*)alloc(WSZ / 2);

    dim3 blk(256);
    int gE = (E + 255) / 256;
    int gN = (n + 255) / 256;
    int gScan = (n + SCAN_B - 1) / SCAN_B;
    int gN32 = (n + 31) / 32;     // 32 nodes per block (8-lane groups)
    int gGemm = MP / 128;         // 391 blocks, 4 waves x 32 rows

    // --- W pre-transpose + x fp16 + bounds ---
    k_wprep<<<(WSZ0 + 255) / 256, blk, 0, stream>>>(W1, wt0, FIN, 2, 0, WSZ0);
    k_wprep<<<(WSZ + 255) / 256, blk, 0, stream>>>(W2, wt1, HD, 8, 1, WSZ);
    k_wprep<<<(WSZ + 255) / 256, blk, 0, stream>>>(W3, wt2, HD, 8, 1, WSZ);
    k_wprep<<<(WSZ + 255) / 256, blk, 0, stream>>>(W4, wt3, HD, 8, 1, WSZ);
    k_split<<<(NN * FIN + 255) / 256, blk, 0, stream>>>(x, x16, NN * FIN);
    k_bounds<<<2, blk, 0, stream>>>(batch, gstart, n);
    // pad slots (kk 28..31) + tail rows must be zero everywhere
    hipMemsetAsync(hi0, 0, (size_t)MP * KP2 * 2, stream);
    hipMemsetAsync(hi1, 0, (size_t)MP * KP2 * 2, stream);
    hipMemsetAsync(hi2, 0, (size_t)MP * KP2 * 2, stream);

    // --- normalization + CSR build ---
    hipMemsetAsync(dis, 0, (size_t)NN * 4, stream);
    hipMemsetAsync(cntd, 0, (size_t)NN * 4, stream);
    hipMemsetAsync(fill, 0, (size_t)NN * 4, stream);
    k_deg<<<gE, blk, 0, stream>>>(src, dst, dis, cntd, E);
    k_node_prep<<<gN, blk, 0, stream>>>(dis, batch, lmax, diag, n);
    k_scan1<<<gScan, blk, 0, stream>>>(cntd, rowst, bsum, n);
    k_scan2<<<1, blk, 0, stream>>>(bsum, gScan);
    k_scan3<<<gScan, blk, 0, stream>>>(rowst, bsum, n);
    k_fillcsr<<<gE, blk, 0, stream>>>(src, dst, batch, lmax, dis, rowst, fill, csr, E);

    // --- 4 Chebyshev layers ---
    const h16* wt[4] = {wt0, wt1, wt2, wt3};
    const float* bl[4] = {b1, b2, b3, b4};
    for (int l = 0; l < 4; l++) {
        int s16 = (l == 0) ? FIN : KP2;
        int nch = (l == 0) ? 2 : 8;
        int ksteps = (l == 0) ? 2 : 8;
        int padded = (l == 0) ? 0 : 1;
        const h16* a0 = (l == 0) ? x16 : hi0;
        int gg = gN32 * nch;
        // Tx1 = prop(Tx0) -> hi1
        k_gather<<<gg, blk, 0, stream>>>(rowst, cntd, csr, diag, a0, a0, hi1, s16, nch, n, 0);
        // Tx2 = 2*prop(Tx1) - Tx0 -> hi2
        k_gather<<<gg, blk, 0, stream>>>(rowst, cntd, csr, diag, hi1, a0, hi2, s16, nch, n, 1);
        // out = relu([Tx0|Tx1|Tx2] @ W + b)
        k_gemm16<<<gGemm, blk, 0, stream>>>(a0, hi1, hi2, s16, ksteps, padded, wt[l], bl[l],
                                            (l == 3) ? H : nullptr,
                                            (l < 3) ? hi0 : nullptr, n);
    }

    // --- fused pool + FC head (no atomics; batch is sorted) ---
    k_pool_fc<<<NG, blk, 0, stream>>>(H, gstart, fcw, fcb, out);
}

// Round 9
// 884.257 us; speedup vs baseline: 2.0564x; 2.0564x over previous
//
#include <hip/hip_runtime.h>
#include <math.h>

#define NN 50000
#define MP 50048          // NN padded to multiple of 128 (32 rows x 4 waves)
#define NE 800000
#define FIN 64
#define HD 200
#define NG 256
#define SCAN_B 256
#define KPAD 224          // HD padded to multiple of 32 for MFMA K-steps
#define NT 13             // 13 * 16 = 208 >= 200 output col tiles

typedef _Float16 h16;
typedef __attribute__((ext_vector_type(8))) _Float16 half8;
typedef __attribute__((ext_vector_type(4))) float float4v;
typedef unsigned long long u64;

// ---------- setup: src out-degree (float) + dst in-degree (int, for CSR) ----------
__global__ void k_deg(const int* __restrict__ src, const int* __restrict__ dst,
                      float* __restrict__ deg, int* __restrict__ cnt_dst, int E) {
    int e = blockIdx.x * blockDim.x + threadIdx.x;
    if (e < E) {
        atomicAdd(&deg[src[e]], 1.0f);
        atomicAdd(&cnt_dst[dst[e]], 1);
    }
}

__global__ void k_node_prep(float* __restrict__ degdis, const int* __restrict__ batch,
                            const float* __restrict__ lmax, float* __restrict__ diag, int n) {
    int i = blockIdx.x * blockDim.x + threadIdx.x;
    if (i < n) {
        float d = degdis[i];
        degdis[i] = (d > 0.f) ? (1.0f / sqrtf(fmaxf(d, 1.0f))) : 0.0f;   // dis
        diag[i] = 2.0f / lmax[batch[i]] - 1.0f;
    }
}

// ---------- exclusive scan over cnt_dst ----------
__global__ void k_scan1(const int* __restrict__ cnt, int* __restrict__ excl,
                        int* __restrict__ bsum, int n) {
    __shared__ int sh[SCAN_B];
    int tid = threadIdx.x;
    int i = blockIdx.x * SCAN_B + tid;
    int v = (i < n) ? cnt[i] : 0;
    sh[tid] = v;
    __syncthreads();
    for (int off = 1; off < SCAN_B; off <<= 1) {
        int t = (tid >= off) ? sh[tid - off] : 0;
        __syncthreads();
        sh[tid] += t;
        __syncthreads();
    }
    if (i < n) excl[i] = sh[tid] - v;
    if (tid == SCAN_B - 1) bsum[blockIdx.x] = sh[tid];
}

__global__ void k_scan2(int* __restrict__ bsum, int nb) {
    __shared__ int sh[SCAN_B];
    int tid = threadIdx.x;
    int v = (tid < nb) ? bsum[tid] : 0;
    sh[tid] = v;
    __syncthreads();
    for (int off = 1; off < SCAN_B; off <<= 1) {
        int t = (tid >= off) ? sh[tid - off] : 0;
        __syncthreads();
        sh[tid] += t;
        __syncthreads();
    }
    if (tid < nb) bsum[tid] = sh[tid] - v;   // exclusive
}

__global__ void k_scan3(int* __restrict__ excl, const int* __restrict__ bsum, int n) {
    int i = blockIdx.x * SCAN_B + threadIdx.x;
    if (i < n) excl[i] += bsum[blockIdx.x];
}

// ---------- permute edges into CSR-by-dst order, packed {src, w} in one u64 ----------
__global__ void k_fillcsr(const int* __restrict__ src, const int* __restrict__ dst,
                          const int* __restrict__ batch, const float* __restrict__ lmax,
                          const float* __restrict__ dis, const int* __restrict__ rowstart,
                          int* __restrict__ fill, u64* __restrict__ csr, int E) {
    int e = blockIdx.x * blockDim.x + threadIdx.x;
    if (e < E) {
        int s = src[e], d = dst[e];
        int pos = rowstart[d] + atomicAdd(&fill[d], 1);
        float w = -dis[s] * dis[d] * (2.0f / lmax[batch[s]]);
        csr[pos] = (unsigned)s | ((u64)__float_as_uint(w) << 32);
    }
}

// ---------- fp32 -> fp16 split for x ----------
__global__ void k_split(const float* __restrict__ x, h16* __restrict__ x16, int total) {
    int i = blockIdx.x * blockDim.x + threadIdx.x;
    if (i < total) x16[i] = (h16)x[i];
}

// ---------- W pre-transpose: f32 [3][fin][HD] -> fp16 [seg][ks][208][32] ----------
__global__ void k_wprep(const float* __restrict__ W, h16* __restrict__ out,
                        int fin, int ksteps, int total) {
    int idx = blockIdx.x * blockDim.x + threadIdx.x;
    if (idx >= total) return;
    int kk = idx & 31;
    int r = idx >> 5;
    int nn = r % 208;
    int r2 = r / 208;
    int ks = r2 % ksteps;
    int seg = r2 / ksteps;
    int k = ks * 32 + kk;
    out[idx] = (nn < HD && k < fin) ? (h16)W[((size_t)seg * fin + k) * HD + nn] : (h16)0.f;
}

// ---------- graph boundaries (batch is sorted) ----------
__global__ void k_bounds(const int* __restrict__ batch, int* __restrict__ gstart, int n) {
    int g = blockIdx.x * blockDim.x + threadIdx.x;
    if (g > NG) return;
    if (g == NG) { gstart[NG] = n; return; }
    int lo = 0, hi = n;
    while (lo < hi) {
        int mid = (lo + hi) >> 1;
        if (batch[mid] < g) lo = mid + 1; else hi = mid;
    }
    gstart[g] = lo;
}

// ---------- propagation (gather, fp16, latency-optimized 8-edge pipeline) ----------
// One lane-group per node: group = 2^lsh lanes (64 for s16=224, 16 for s16=64).
// Edge loop unrolled x8: 8 broadcast CSR loads then 8 INDEPENDENT row loads in
// flight (breaks the csr->row dependent chain that capped R5 at 3.45 TB/s).
// mode 0: v = gath + diag*hin        mode 1: v = 2*(gath + diag*hin) - hin0
__global__ __launch_bounds__(256) void k_gather(
    const int* __restrict__ rowstart, const int* __restrict__ rowcnt,
    const u64* __restrict__ csr, const float* __restrict__ diag,
    const h16* __restrict__ hin16, const h16* __restrict__ h016,
    h16* __restrict__ hout16, int s16, int lsh, int n, int mode) {
    int per = 256 >> lsh;
    int i = blockIdx.x * per + (threadIdx.x >> lsh);
    if (i >= n) return;
    int lane = threadIdx.x & ((1 << lsh) - 1);
    int c0 = lane * 4;
    if (c0 >= s16) return;
    int start = rowstart[i], cnt = rowcnt[i];
    float a0 = 0.f, a1 = 0.f, a2 = 0.f, a3 = 0.f;
    union U { uint2 u; h16 h[4]; };
    const u64* cp = csr + start;
    int k = 0;
    for (; k + 7 < cnt; k += 8) {
        u64 e[8];
#pragma unroll
        for (int j = 0; j < 8; ++j) e[j] = cp[k + j];           // broadcast, independent
        U p[8];
#pragma unroll
        for (int j = 0; j < 8; ++j)                              // 8 rows in flight
            p[j].u = *(const uint2*)(hin16 + (size_t)(unsigned)(e[j] & 0xffffffffu) * s16 + c0);
#pragma unroll
        for (int j = 0; j < 8; ++j) {
            float w = __uint_as_float((unsigned)(e[j] >> 32));
            a0 += w * (float)p[j].h[0];
            a1 += w * (float)p[j].h[1];
            a2 += w * (float)p[j].h[2];
            a3 += w * (float)p[j].h[3];
        }
    }
    for (; k + 1 < cnt; k += 2) {
        u64 e0 = cp[k], e1 = cp[k + 1];
        U p0, p1;
        p0.u = *(const uint2*)(hin16 + (size_t)(unsigned)(e0 & 0xffffffffu) * s16 + c0);
        p1.u = *(const uint2*)(hin16 + (size_t)(unsigned)(e1 & 0xffffffffu) * s16 + c0);
        float w0 = __uint_as_float((unsigned)(e0 >> 32));
        float w1 = __uint_as_float((unsigned)(e1 >> 32));
        a0 += w0 * (float)p0.h[0] + w1 * (float)p1.h[0];
        a1 += w0 * (float)p0.h[1] + w1 * (float)p1.h[1];
        a2 += w0 * (float)p0.h[2] + w1 * (float)p1.h[2];
        a3 += w0 * (float)p0.h[3] + w1 * (float)p1.h[3];
    }
    if (k < cnt) {
        u64 e0 = cp[k];
        U p0;
        p0.u = *(const uint2*)(hin16 + (size_t)(unsigned)(e0 & 0xffffffffu) * s16 + c0);
        float w0 = __uint_as_float((unsigned)(e0 >> 32));
        a0 += w0 * (float)p0.h[0];
        a1 += w0 * (float)p0.h[1];
        a2 += w0 * (float)p0.h[2];
        a3 += w0 * (float)p0.h[3];
    }
    float dg = diag[i];
    U hs; hs.u = *(const uint2*)(hin16 + (size_t)i * s16 + c0);
    float v0 = a0 + dg * (float)hs.h[0];
    float v1 = a1 + dg * (float)hs.h[1];
    float v2 = a2 + dg * (float)hs.h[2];
    float v3 = a3 + dg * (float)hs.h[3];
    if (mode == 1) {
        U h0; h0.u = *(const uint2*)(h016 + (size_t)i * s16 + c0);
        v0 = 2.f * v0 - (float)h0.h[0];
        v1 = 2.f * v1 - (float)h0.h[1];
        v2 = 2.f * v2 - (float)h0.h[2];
        v3 = 2.f * v3 - (float)h0.h[3];
    }
    U o;
    o.h[0] = (h16)v0; o.h[1] = (h16)v1; o.h[2] = (h16)v2; o.h[3] = (h16)v3;
    *(uint2*)(hout16 + (size_t)i * s16 + c0) = o.u;
}

// ---------- MFMA fp16 GEMM, barrier-free: out = relu([A0|A1|A2] @ W + b) ----------
// Each wave: 32 rows x 208 cols (2 row-frags share each B-fragment).
__global__ __launch_bounds__(256) void k_gemm16(
    const h16* __restrict__ A0, const h16* __restrict__ A1, const h16* __restrict__ A2,
    int strideA, int ksteps,
    const h16* __restrict__ Wt, const float* __restrict__ bias,
    float* __restrict__ outF, h16* __restrict__ out16, int n) {
    int tid = threadIdx.x;
    int wave = tid >> 6, lane = tid & 63;
    int nq = lane & 15, quad = lane >> 4;
    int row0 = (blockIdx.x * 4 + wave) * 32;
    const h16* Aseg[3] = {A0, A1, A2};

    float4v acc[2][NT];
#pragma unroll
    for (int r = 0; r < 2; r++)
#pragma unroll
        for (int t = 0; t < NT; t++) acc[r][t] = (float4v)0.f;

    for (int seg = 0; seg < 3; ++seg) {
        const h16* Ab = Aseg[seg] + (size_t)(row0 + nq) * strideA + quad * 8;
        const h16* Bb = Wt + (size_t)seg * ksteps * 208 * 32 + (size_t)nq * 32 + quad * 8;
        for (int ks = 0; ks < ksteps; ++ks) {
            half8 af0 = *(const half8*)(Ab + ks * 32);
            half8 af1 = *(const half8*)(Ab + 16 * strideA + ks * 32);
            const h16* Bk = Bb + (size_t)ks * 208 * 32;
#pragma unroll
            for (int t = 0; t < NT; ++t) {
                half8 bf = *(const half8*)(Bk + t * 16 * 32);
                acc[0][t] = __builtin_amdgcn_mfma_f32_16x16x32_f16(af0, bf, acc[0][t], 0, 0, 0);
                acc[1][t] = __builtin_amdgcn_mfma_f32_16x16x32_f16(af1, bf, acc[1][t], 0, 0, 0);
            }
        }
    }
#pragma unroll
    for (int r = 0; r < 2; ++r) {
        int rowb = row0 + r * 16 + quad * 4;
#pragma unroll
        for (int t = 0; t < NT; ++t) {
            int col = t * 16 + nq;
            if (col >= HD) continue;
            float bj = bias[col];
#pragma unroll
            for (int g = 0; g < 4; ++g) {
                int row = rowb + g;
                if (row < n) {
                    float v = fmaxf(acc[r][t][g] + bj, 0.0f);
                    if (outF)  outF[(size_t)row * HD + col] = v;
                    if (out16) out16[(size_t)row * KPAD + col] = (h16)v;
                }
            }
        }
    }
}

// ---------- fused segmented pool (mean+max) + FC + log_softmax: one block per graph ----------
__global__ __launch_bounds__(256) void k_pool_fc(
    const float* __restrict__ Hf, const int* __restrict__ gstart,
    const float* __restrict__ fcw, const float* __restrict__ fcb,
    float* __restrict__ out) {
    __shared__ float red[8];
    int g = blockIdx.x;
    int j = threadIdx.x;
    int i0 = gstart[g], i1 = gstart[g + 1];
    float s0 = 0.f, s1 = 0.f, s2 = 0.f, s3 = 0.f, mx = 0.f;   // post-ReLU: max >= 0
    if (j < HD) {
        int i = i0;
        for (; i + 3 < i1; i += 4) {
            float v0 = Hf[(size_t)i * HD + j];
            float v1 = Hf[(size_t)(i + 1) * HD + j];
            float v2 = Hf[(size_t)(i + 2) * HD + j];
            float v3 = Hf[(size_t)(i + 3) * HD + j];
            s0 += v0; s1 += v1; s2 += v2; s3 += v3;
            mx = fmaxf(mx, fmaxf(fmaxf(v0, v1), fmaxf(v2, v3)));
        }
        for (; i < i1; ++i) {
            float v = Hf[(size_t)i * HD + j];
            s0 += v; mx = fmaxf(mx, v);
        }
    }
    float cntf = (float)(i1 - i0);
    float mean = (s0 + s1 + s2 + s3) / fmaxf(cntf, 1.f);
    float p0 = 0.f, p1 = 0.f;
    if (j < HD) {
        p0 = mean * fcw[2 * j]     + mx * fcw[2 * (HD + j)];
        p1 = mean * fcw[2 * j + 1] + mx * fcw[2 * (HD + j) + 1];
    }
#pragma unroll
    for (int o = 32; o > 0; o >>= 1) {
        p0 += __shfl_down(p0, o);
        p1 += __shfl_down(p1, o);
    }
    int wave = j >> 6, lane = j & 63;
    if (lane == 0) { red[wave * 2] = p0; red[wave * 2 + 1] = p1; }
    __syncthreads();
    if (j == 0) {
        float z0 = red[0] + red[2] + red[4] + red[6] + fcb[0];
        float z1 = red[1] + red[3] + red[5] + red[7] + fcb[1];
        float m = fmaxf(z0, z1);
        float lse = m + logf(expf(z0 - m) + expf(z1 - m));
        out[g * 2 + 0] = z0 - lse;
        out[g * 2 + 1] = z1 - lse;
    }
}

extern "C" void kernel_launch(void* const* d_in, const int* in_sizes, int n_in,
                              void* d_out, int out_size, void* d_ws, size_t ws_size,
                              hipStream_t stream) {
    const float* x     = (const float*)d_in[0];
    const int*   edge  = (const int*)d_in[1];
    const int*   batch = (const int*)d_in[2];
    const float* lmax  = (const float*)d_in[3];
    const float* W1 = (const float*)d_in[4];  const float* b1 = (const float*)d_in[5];
    const float* W2 = (const float*)d_in[6];  const float* b2 = (const float*)d_in[7];
    const float* W3 = (const float*)d_in[8];  const float* b3 = (const float*)d_in[9];
    const float* W4 = (const float*)d_in[10]; const float* b4 = (const float*)d_in[11];
    const float* fcw = (const float*)d_in[12]; const float* fcb = (const float*)d_in[13];
    float* out = (float*)d_out;

    const int n = NN, E = NE;
    const int* src = edge;
    const int* dst = edge + E;

    // workspace layout (float units, each buffer 16B-aligned)
    float* ws = (float*)d_ws;
    size_t off = 0;
    auto alloc = [&](size_t nfloats) { float* p = ws + off; off += (nfloats + 3) & ~(size_t)3; return p; };
    float* dis    = alloc(NN);
    float* diag   = alloc(NN);
    int*   cntd   = (int*)alloc(NN);
    int*   rowst  = (int*)alloc(NN);
    int*   fill   = (int*)alloc(NN);
    int*   bsum   = (int*)alloc(SCAN_B);
    u64*   csr    = (u64*)alloc((size_t)NE * 2);          // packed {src, w}
    int*   gstart = (int*)alloc(NG + 1);
    float* H      = alloc((size_t)MP * HD);               // f32 final-layer features (pool)
    h16*   x16    = (h16*)alloc((size_t)MP * FIN / 2);    // fp16 x (stride 64)
    h16*   hi0    = (h16*)alloc((size_t)MP * KPAD / 2);   // fp16 Tx0 (in-place per layer)
    h16*   hi1    = (h16*)alloc((size_t)MP * KPAD / 2);   // fp16 Tx1
    h16*   hi2    = (h16*)alloc((size_t)MP * KPAD / 2);   // fp16 Tx2
    const int WSZ0 = 3 * 2 * 208 * 32;                    // layer 0 (fin=64, ksteps=2)
    const int WSZ  = 3 * 7 * 208 * 32;                    // layers 1-3 (fin=200, ksteps=7)
    h16* wt0 = (h16*)alloc(WSZ0 / 2);
    h16* wt1 = (h16*)alloc(WSZ / 2);
    h16* wt2 = (h16*)alloc(WSZ / 2);
    h16* wt3 = (h16*)alloc(WSZ / 2);

    dim3 blk(256);
    int gE = (E + 255) / 256;
    int gN = (n + 255) / 256;
    int gScan = (n + SCAN_B - 1) / SCAN_B;
    int gGemm = MP / 128;         // 391 blocks, 4 waves x 32 rows

    // --- W pre-transpose (L2-resident fp16 fragments) + x fp16 + bounds ---
    k_wprep<<<(WSZ0 + 255) / 256, blk, 0, stream>>>(W1, wt0, FIN, 2, WSZ0);
    k_wprep<<<(WSZ + 255) / 256, blk, 0, stream>>>(W2, wt1, HD, 7, WSZ);
    k_wprep<<<(WSZ + 255) / 256, blk, 0, stream>>>(W3, wt2, HD, 7, WSZ);
    k_wprep<<<(WSZ + 255) / 256, blk, 0, stream>>>(W4, wt3, HD, 7, WSZ);
    k_split<<<(NN * FIN + 255) / 256, blk, 0, stream>>>(x, x16, NN * FIN);
    k_bounds<<<2, blk, 0, stream>>>(batch, gstart, n);
    // hi0 pads (cols 200..223 + tail rows) must be zero: gemm only writes cols<200
    hipMemsetAsync(hi0, 0, (size_t)MP * KPAD * 2, stream);

    // --- normalization + CSR build ---
    hipMemsetAsync(dis, 0, (size_t)NN * 4, stream);
    hipMemsetAsync(cntd, 0, (size_t)NN * 4, stream);
    hipMemsetAsync(fill, 0, (size_t)NN * 4, stream);
    k_deg<<<gE, blk, 0, stream>>>(src, dst, dis, cntd, E);
    k_node_prep<<<gN, blk, 0, stream>>>(dis, batch, lmax, diag, n);
    k_scan1<<<gScan, blk, 0, stream>>>(cntd, rowst, bsum, n);
    k_scan2<<<1, blk, 0, stream>>>(bsum, gScan);
    k_scan3<<<gScan, blk, 0, stream>>>(rowst, bsum, n);
    k_fillcsr<<<gE, blk, 0, stream>>>(src, dst, batch, lmax, dis, rowst, fill, csr, E);

    // --- 4 Chebyshev layers ---
    const h16* wt[4] = {wt0, wt1, wt2, wt3};
    const float* bl[4] = {b1, b2, b3, b4};
    for (int l = 0; l < 4; l++) {
        int s16 = (l == 0) ? FIN : KPAD;
        int lsh = (l == 0) ? 4 : 6;                  // 16-lane groups (l0) / full wave
        int per = 256 >> lsh;
        int gGat = (n + per - 1) / per;
        int ksteps = (l == 0) ? 2 : 7;
        const h16* a0 = (l == 0) ? x16 : hi0;
        // Tx1 = prop(Tx0) -> hi1
        k_gather<<<gGat, blk, 0, stream>>>(rowst, cntd, csr, diag, a0, a0, hi1, s16, lsh, n, 0);
        // Tx2 = 2*prop(Tx1) - Tx0 -> hi2
        k_gather<<<gGat, blk, 0, stream>>>(rowst, cntd, csr, diag, hi1, a0, hi2, s16, lsh, n, 1);
        // out = relu([Tx0|Tx1|Tx2] @ W + b)
        k_gemm16<<<gGemm, blk, 0, stream>>>(a0, hi1, hi2, s16, ksteps, wt[l], bl[l],
                                            (l == 3) ? H : nullptr,
                                            (l < 3) ? hi0 : nullptr, n);
    }

    // --- fused pool + FC head (no atomics; batch is sorted) ---
    k_pool_fc<<<NG, blk, 0, stream>>>(H, gstart, fcw, fcb, out);
}

// Round 10
// 851.481 us; speedup vs baseline: 2.1356x; 1.0385x over previous
//
#include <hip/hip_runtime.h>
#include <math.h>

#define NN 50000
#define MP 50048          // NN padded to multiple of 128 (32 rows x 4 waves)
#define NE 800000
#define FIN 64
#define HD 200
#define NG 256
#define SCAN_B 256
#define KPAD 224          // HD padded to multiple of 32 for MFMA K-steps
#define NT 13             // 13 * 16 = 208 >= 200 output col tiles
#define HB 12544          // LDS histogram packed dwords (covers 25088 nodes/pass)
#define PER_B 3125        // NE / 256 edges per histogram block

typedef _Float16 h16;
typedef __attribute__((ext_vector_type(8))) _Float16 half8;
typedef __attribute__((ext_vector_type(4))) float float4v;
typedef unsigned long long u64;

// ---------- histogram: per-block LDS counts (u16-packed, 2 node-range passes) ----------
// Zero global atomics: partial[pass][block][HB] flushed coalesced, reduced below.
__global__ __launch_bounds__(256) void k_hist(const int* __restrict__ idx,
                                              unsigned* __restrict__ partial, int E) {
    __shared__ unsigned h[HB];
    int tid = threadIdx.x;
    int e0 = blockIdx.x * PER_B;
    int v[13];
#pragma unroll
    for (int j = 0; j < 13; ++j) {
        int o = j * 256 + tid;
        v[j] = (o < PER_B) ? idx[e0 + o] : -1;
    }
#pragma unroll
    for (int pass = 0; pass < 2; ++pass) {
        for (int t = tid; t < HB; t += 256) h[t] = 0;
        __syncthreads();
        int lo = pass * (2 * HB);
#pragma unroll
        for (int j = 0; j < 13; ++j) {
            int vv = v[j] - lo;
            if (vv >= 0 && vv < 2 * HB)
                atomicAdd(&h[vv >> 1], (vv & 1) ? 0x10000u : 1u);
        }
        __syncthreads();
        unsigned* pb = partial + ((size_t)pass * 256 + blockIdx.x) * HB;
        for (int t = tid; t < HB; t += 256) pb[t] = h[t];
        __syncthreads();
    }
}

// sum 256 per-block partials -> int counts (both packed halves)
__global__ void k_hreduce(const unsigned* __restrict__ partial, int* __restrict__ cnt, int n) {
    int i = blockIdx.x * blockDim.x + threadIdx.x;
    if (i >= 2 * HB) return;
    int pass = i / HB, p = i - pass * HB;
    const unsigned* pb = partial + (size_t)pass * 256 * HB + p;
    unsigned s = 0;
    for (int b = 0; b < 256; ++b) s += pb[(size_t)b * HB];
    int n0 = pass * 2 * HB + 2 * p;
    if (n0 < n)     cnt[n0]     = (int)(s & 0xffffu);
    if (n0 + 1 < n) cnt[n0 + 1] = (int)(s >> 16);
}

__global__ void k_node_prep(const int* __restrict__ degi, const int* __restrict__ batch,
                            const float* __restrict__ lmax, float* __restrict__ dis,
                            float* __restrict__ diag, int n) {
    int i = blockIdx.x * blockDim.x + threadIdx.x;
    if (i < n) {
        int d = degi[i];
        dis[i] = (d > 0) ? (1.0f / sqrtf((float)d)) : 0.0f;
        diag[i] = 2.0f / lmax[batch[i]] - 1.0f;
    }
}

// ---------- exclusive scan over cnt_dst ----------
__global__ void k_scan1(const int* __restrict__ cnt, int* __restrict__ excl,
                        int* __restrict__ bsum, int n) {
    __shared__ int sh[SCAN_B];
    int tid = threadIdx.x;
    int i = blockIdx.x * SCAN_B + tid;
    int v = (i < n) ? cnt[i] : 0;
    sh[tid] = v;
    __syncthreads();
    for (int off = 1; off < SCAN_B; off <<= 1) {
        int t = (tid >= off) ? sh[tid - off] : 0;
        __syncthreads();
        sh[tid] += t;
        __syncthreads();
    }
    if (i < n) excl[i] = sh[tid] - v;
    if (tid == SCAN_B - 1) bsum[blockIdx.x] = sh[tid];
}

__global__ void k_scan2(int* __restrict__ bsum, int nb) {
    __shared__ int sh[SCAN_B];
    int tid = threadIdx.x;
    int v = (tid < nb) ? bsum[tid] : 0;
    sh[tid] = v;
    __syncthreads();
    for (int off = 1; off < SCAN_B; off <<= 1) {
        int t = (tid >= off) ? sh[tid - off] : 0;
        __syncthreads();
        sh[tid] += t;
        __syncthreads();
    }
    if (tid < nb) bsum[tid] = sh[tid] - v;   // exclusive
}

__global__ void k_scan3(int* __restrict__ excl, const int* __restrict__ bsum, int n) {
    int i = blockIdx.x * SCAN_B + threadIdx.x;
    if (i < n) excl[i] += bsum[blockIdx.x];
}

// ---------- permute edges into CSR-by-dst order, packed {src, w} in one u64 ----------
__global__ void k_fillcsr(const int* __restrict__ src, const int* __restrict__ dst,
                          const int* __restrict__ batch, const float* __restrict__ lmax,
                          const float* __restrict__ dis, const int* __restrict__ rowstart,
                          int* __restrict__ fill, u64* __restrict__ csr, int E) {
    int e = blockIdx.x * blockDim.x + threadIdx.x;
    if (e < E) {
        int s = src[e], d = dst[e];
        int pos = rowstart[d] + atomicAdd(&fill[d], 1);
        float w = -dis[s] * dis[d] * (2.0f / lmax[batch[s]]);
        csr[pos] = (unsigned)s | ((u64)__float_as_uint(w) << 32);
    }
}

// ---------- fp32 -> fp16 split for x ----------
__global__ void k_split(const float* __restrict__ x, h16* __restrict__ x16, int total) {
    int i = blockIdx.x * blockDim.x + threadIdx.x;
    if (i < total) x16[i] = (h16)x[i];
}

// ---------- W pre-transpose: f32 [3][fin][HD] -> fp16 [seg][ks][208][32] ----------
__global__ void k_wprep(const float* __restrict__ W, h16* __restrict__ out,
                        int fin, int ksteps, int total) {
    int idx = blockIdx.x * blockDim.x + threadIdx.x;
    if (idx >= total) return;
    int kk = idx & 31;
    int r = idx >> 5;
    int nn = r % 208;
    int r2 = r / 208;
    int ks = r2 % ksteps;
    int seg = r2 / ksteps;
    int k = ks * 32 + kk;
    out[idx] = (nn < HD && k < fin) ? (h16)W[((size_t)seg * fin + k) * HD + nn] : (h16)0.f;
}

// ---------- graph boundaries (batch is sorted) ----------
__global__ void k_bounds(const int* __restrict__ batch, int* __restrict__ gstart, int n) {
    int g = blockIdx.x * blockDim.x + threadIdx.x;
    if (g > NG) return;
    if (g == NG) { gstart[NG] = n; return; }
    int lo = 0, hi = n;
    while (lo < hi) {
        int mid = (lo + hi) >> 1;
        if (batch[mid] < g) lo = mid + 1; else hi = mid;
    }
    gstart[g] = lo;
}

// ---------- propagation (gather, fp16, latency-optimized 8-edge pipeline) ----------
// One lane-group per node: group = 2^lsh lanes (64 for s16=224, 16 for s16=64).
// mode 0: v = gath + diag*hin        mode 1: v = 2*(gath + diag*hin) - hin0
__global__ __launch_bounds__(256) void k_gather(
    const int* __restrict__ rowstart, const int* __restrict__ rowcnt,
    const u64* __restrict__ csr, const float* __restrict__ diag,
    const h16* __restrict__ hin16, const h16* __restrict__ h016,
    h16* __restrict__ hout16, int s16, int lsh, int n, int mode) {
    int per = 256 >> lsh;
    int i = blockIdx.x * per + (threadIdx.x >> lsh);
    if (i >= n) return;
    int lane = threadIdx.x & ((1 << lsh) - 1);
    int c0 = lane * 4;
    if (c0 >= s16) return;
    int start = rowstart[i], cnt = rowcnt[i];
    float a0 = 0.f, a1 = 0.f, a2 = 0.f, a3 = 0.f;
    union U { uint2 u; h16 h[4]; };
    const u64* cp = csr + start;
    int k = 0;
    for (; k + 7 < cnt; k += 8) {
        u64 e[8];
#pragma unroll
        for (int j = 0; j < 8; ++j) e[j] = cp[k + j];           // broadcast, independent
        U p[8];
#pragma unroll
        for (int j = 0; j < 8; ++j)                              // 8 rows in flight
            p[j].u = *(const uint2*)(hin16 + (size_t)(unsigned)(e[j] & 0xffffffffu) * s16 + c0);
#pragma unroll
        for (int j = 0; j < 8; ++j) {
            float w = __uint_as_float((unsigned)(e[j] >> 32));
            a0 += w * (float)p[j].h[0];
            a1 += w * (float)p[j].h[1];
            a2 += w * (float)p[j].h[2];
            a3 += w * (float)p[j].h[3];
        }
    }
    for (; k + 1 < cnt; k += 2) {
        u64 e0 = cp[k], e1 = cp[k + 1];
        U p0, p1;
        p0.u = *(const uint2*)(hin16 + (size_t)(unsigned)(e0 & 0xffffffffu) * s16 + c0);
        p1.u = *(const uint2*)(hin16 + (size_t)(unsigned)(e1 & 0xffffffffu) * s16 + c0);
        float w0 = __uint_as_float((unsigned)(e0 >> 32));
        float w1 = __uint_as_float((unsigned)(e1 >> 32));
        a0 += w0 * (float)p0.h[0] + w1 * (float)p1.h[0];
        a1 += w0 * (float)p0.h[1] + w1 * (float)p1.h[1];
        a2 += w0 * (float)p0.h[2] + w1 * (float)p1.h[2];
        a3 += w0 * (float)p0.h[3] + w1 * (float)p1.h[3];
    }
    if (k < cnt) {
        u64 e0 = cp[k];
        U p0;
        p0.u = *(const uint2*)(hin16 + (size_t)(unsigned)(e0 & 0xffffffffu) * s16 + c0);
        float w0 = __uint_as_float((unsigned)(e0 >> 32));
        a0 += w0 * (float)p0.h[0];
        a1 += w0 * (float)p0.h[1];
        a2 += w0 * (float)p0.h[2];
        a3 += w0 * (float)p0.h[3];
    }
    float dg = diag[i];
    U hs; hs.u = *(const uint2*)(hin16 + (size_t)i * s16 + c0);
    float v0 = a0 + dg * (float)hs.h[0];
    float v1 = a1 + dg * (float)hs.h[1];
    float v2 = a2 + dg * (float)hs.h[2];
    float v3 = a3 + dg * (float)hs.h[3];
    if (mode == 1) {
        U h0; h0.u = *(const uint2*)(h016 + (size_t)i * s16 + c0);
        v0 = 2.f * v0 - (float)h0.h[0];
        v1 = 2.f * v1 - (float)h0.h[1];
        v2 = 2.f * v2 - (float)h0.h[2];
        v3 = 2.f * v3 - (float)h0.h[3];
    }
    U o;
    o.h[0] = (h16)v0; o.h[1] = (h16)v1; o.h[2] = (h16)v2; o.h[3] = (h16)v3;
    *(uint2*)(hout16 + (size_t)i * s16 + c0) = o.u;
}

// ---------- MFMA fp16 GEMM, barrier-free: out = relu([A0|A1|A2] @ W + b) ----------
// Each wave: 32 rows x 208 cols (2 row-frags share each B-fragment).
__global__ __launch_bounds__(256) void k_gemm16(
    const h16* __restrict__ A0, const h16* __restrict__ A1, const h16* __restrict__ A2,
    int strideA, int ksteps,
    const h16* __restrict__ Wt, const float* __restrict__ bias,
    float* __restrict__ outF, h16* __restrict__ out16, int n) {
    int tid = threadIdx.x;
    int wave = tid >> 6, lane = tid & 63;
    int nq = lane & 15, quad = lane >> 4;
    int row0 = (blockIdx.x * 4 + wave) * 32;
    const h16* Aseg[3] = {A0, A1, A2};

    float4v acc[2][NT];
#pragma unroll
    for (int r = 0; r < 2; r++)
#pragma unroll
        for (int t = 0; t < NT; t++) acc[r][t] = (float4v)0.f;

    for (int seg = 0; seg < 3; ++seg) {
        const h16* Ab = Aseg[seg] + (size_t)(row0 + nq) * strideA + quad * 8;
        const h16* Bb = Wt + (size_t)seg * ksteps * 208 * 32 + (size_t)nq * 32 + quad * 8;
        for (int ks = 0; ks < ksteps; ++ks) {
            half8 af0 = *(const half8*)(Ab + ks * 32);
            half8 af1 = *(const half8*)(Ab + 16 * strideA + ks * 32);
            const h16* Bk = Bb + (size_t)ks * 208 * 32;
#pragma unroll
            for (int t = 0; t < NT; ++t) {
                half8 bf = *(const half8*)(Bk + t * 16 * 32);
                acc[0][t] = __builtin_amdgcn_mfma_f32_16x16x32_f16(af0, bf, acc[0][t], 0, 0, 0);
                acc[1][t] = __builtin_amdgcn_mfma_f32_16x16x32_f16(af1, bf, acc[1][t], 0, 0, 0);
            }
        }
    }
#pragma unroll
    for (int r = 0; r < 2; ++r) {
        int rowb = row0 + r * 16 + quad * 4;
#pragma unroll
        for (int t = 0; t < NT; ++t) {
            int col = t * 16 + nq;
            if (col >= HD) continue;
            float bj = bias[col];
#pragma unroll
            for (int g = 0; g < 4; ++g) {
                int row = rowb + g;
                if (row < n) {
                    float v = fmaxf(acc[r][t][g] + bj, 0.0f);
                    if (outF)  outF[(size_t)row * HD + col] = v;
                    if (out16) out16[(size_t)row * KPAD + col] = (h16)v;
                }
            }
        }
    }
}

// ---------- fused segmented pool (mean+max) + FC + log_softmax: one block per graph ----------
__global__ __launch_bounds__(256) void k_pool_fc(
    const float* __restrict__ Hf, const int* __restrict__ gstart,
    const float* __restrict__ fcw, const float* __restrict__ fcb,
    float* __restrict__ out) {
    __shared__ float red[8];
    int g = blockIdx.x;
    int j = threadIdx.x;
    int i0 = gstart[g], i1 = gstart[g + 1];
    float s0 = 0.f, s1 = 0.f, s2 = 0.f, s3 = 0.f, mx = 0.f;   // post-ReLU: max >= 0
    if (j < HD) {
        int i = i0;
        for (; i + 3 < i1; i += 4) {
            float v0 = Hf[(size_t)i * HD + j];
            float v1 = Hf[(size_t)(i + 1) * HD + j];
            float v2 = Hf[(size_t)(i + 2) * HD + j];
            float v3 = Hf[(size_t)(i + 3) * HD + j];
            s0 += v0; s1 += v1; s2 += v2; s3 += v3;
            mx = fmaxf(mx, fmaxf(fmaxf(v0, v1), fmaxf(v2, v3)));
        }
        for (; i < i1; ++i) {
            float v = Hf[(size_t)i * HD + j];
            s0 += v; mx = fmaxf(mx, v);
        }
    }
    float cntf = (float)(i1 - i0);
    float mean = (s0 + s1 + s2 + s3) / fmaxf(cntf, 1.f);
    float p0 = 0.f, p1 = 0.f;
    if (j < HD) {
        p0 = mean * fcw[2 * j]     + mx * fcw[2 * (HD + j)];
        p1 = mean * fcw[2 * j + 1] + mx * fcw[2 * (HD + j) + 1];
    }
#pragma unroll
    for (int o = 32; o > 0; o >>= 1) {
        p0 += __shfl_down(p0, o);
        p1 += __shfl_down(p1, o);
    }
    int wave = j >> 6, lane = j & 63;
    if (lane == 0) { red[wave * 2] = p0; red[wave * 2 + 1] = p1; }
    __syncthreads();
    if (j == 0) {
        float z0 = red[0] + red[2] + red[4] + red[6] + fcb[0];
        float z1 = red[1] + red[3] + red[5] + red[7] + fcb[1];
        float m = fmaxf(z0, z1);
        float lse = m + logf(expf(z0 - m) + expf(z1 - m));
        out[g * 2 + 0] = z0 - lse;
        out[g * 2 + 1] = z1 - lse;
    }
}

extern "C" void kernel_launch(void* const* d_in, const int* in_sizes, int n_in,
                              void* d_out, int out_size, void* d_ws, size_t ws_size,
                              hipStream_t stream) {
    const float* x     = (const float*)d_in[0];
    const int*   edge  = (const int*)d_in[1];
    const int*   batch = (const int*)d_in[2];
    const float* lmax  = (const float*)d_in[3];
    const float* W1 = (const float*)d_in[4];  const float* b1 = (const float*)d_in[5];
    const float* W2 = (const float*)d_in[6];  const float* b2 = (const float*)d_in[7];
    const float* W3 = (const float*)d_in[8];  const float* b3 = (const float*)d_in[9];
    const float* W4 = (const float*)d_in[10]; const float* b4 = (const float*)d_in[11];
    const float* fcw = (const float*)d_in[12]; const float* fcb = (const float*)d_in[13];
    float* out = (float*)d_out;

    const int n = NN, E = NE;
    const int* src = edge;
    const int* dst = edge + E;

    // workspace layout (float units, each buffer 16B-aligned)
    float* ws = (float*)d_ws;
    size_t off = 0;
    auto alloc = [&](size_t nfloats) { float* p = ws + off; off += (nfloats + 3) & ~(size_t)3; return p; };
    int*   degi   = (int*)alloc(NN);
    float* dis    = alloc(NN);
    float* diag   = alloc(NN);
    int*   cntd   = (int*)alloc(NN);
    int*   rowst  = (int*)alloc(NN);
    int*   fill   = (int*)alloc(NN);
    int*   bsum   = (int*)alloc(SCAN_B);
    u64*   csr    = (u64*)alloc((size_t)NE * 2);          // packed {src, w}
    int*   gstart = (int*)alloc(NG + 1);
    unsigned* hpart = (unsigned*)alloc((size_t)2 * 256 * HB);  // histogram partials (25.7 MB)
    float* H      = alloc((size_t)MP * HD);               // f32 final-layer features (pool)
    h16*   x16    = (h16*)alloc((size_t)MP * FIN / 2);    // fp16 x (stride 64)
    h16*   hi0    = (h16*)alloc((size_t)MP * KPAD / 2);   // fp16 Tx0 (in-place per layer)
    h16*   hi1    = (h16*)alloc((size_t)MP * KPAD / 2);   // fp16 Tx1
    h16*   hi2    = (h16*)alloc((size_t)MP * KPAD / 2);   // fp16 Tx2
    const int WSZ0 = 3 * 2 * 208 * 32;                    // layer 0 (fin=64, ksteps=2)
    const int WSZ  = 3 * 7 * 208 * 32;                    // layers 1-3 (fin=200, ksteps=7)
    h16* wt0 = (h16*)alloc(WSZ0 / 2);
    h16* wt1 = (h16*)alloc(WSZ / 2);
    h16* wt2 = (h16*)alloc(WSZ / 2);
    h16* wt3 = (h16*)alloc(WSZ / 2);

    dim3 blk(256);
    int gE = (E + 255) / 256;
    int gN = (n + 255) / 256;
    int gScan = (n + SCAN_B - 1) / SCAN_B;
    int gGemm = MP / 128;         // 391 blocks, 4 waves x 32 rows
    int gHR = (2 * HB + 255) / 256;

    // --- W pre-transpose (L2-resident fp16 fragments) + x fp16 + bounds ---
    k_wprep<<<(WSZ0 + 255) / 256, blk, 0, stream>>>(W1, wt0, FIN, 2, WSZ0);
    k_wprep<<<(WSZ + 255) / 256, blk, 0, stream>>>(W2, wt1, HD, 7, WSZ);
    k_wprep<<<(WSZ + 255) / 256, blk, 0, stream>>>(W3, wt2, HD, 7, WSZ);
    k_wprep<<<(WSZ + 255) / 256, blk, 0, stream>>>(W4, wt3, HD, 7, WSZ);
    k_split<<<(NN * FIN + 255) / 256, blk, 0, stream>>>(x, x16, NN * FIN);
    k_bounds<<<2, blk, 0, stream>>>(batch, gstart, n);
    // hi0 pads (cols 200..223 + tail rows) must be zero: gemm only writes cols<200
    hipMemsetAsync(hi0, 0, (size_t)MP * KPAD * 2, stream);

    // --- degrees via LDS histograms (no global atomics) ---
    k_hist<<<256, blk, 0, stream>>>(src, hpart, E);
    k_hreduce<<<gHR, blk, 0, stream>>>(hpart, degi, n);
    k_hist<<<256, blk, 0, stream>>>(dst, hpart, E);
    k_hreduce<<<gHR, blk, 0, stream>>>(hpart, cntd, n);
    k_node_prep<<<gN, blk, 0, stream>>>(degi, batch, lmax, dis, diag, n);

    // --- CSR build ---
    hipMemsetAsync(fill, 0, (size_t)NN * 4, stream);
    k_scan1<<<gScan, blk, 0, stream>>>(cntd, rowst, bsum, n);
    k_scan2<<<1, blk, 0, stream>>>(bsum, gScan);
    k_scan3<<<gScan, blk, 0, stream>>>(rowst, bsum, n);
    k_fillcsr<<<gE, blk, 0, stream>>>(src, dst, batch, lmax, dis, rowst, fill, csr, E);

    // --- 4 Chebyshev layers ---
    const h16* wt[4] = {wt0, wt1, wt2, wt3};
    const float* bl[4] = {b1, b2, b3, b4};
    for (int l = 0; l < 4; l++) {
        int s16 = (l == 0) ? FIN : KPAD;
        int lsh = (l == 0) ? 4 : 6;                  // 16-lane groups (l0) / full wave
        int per = 256 >> lsh;
        int gGat = (n + per - 1) / per;
        int ksteps = (l == 0) ? 2 : 7;
        const h16* a0 = (l == 0) ? x16 : hi0;
        // Tx1 = prop(Tx0) -> hi1
        k_gather<<<gGat, blk, 0, stream>>>(rowst, cntd, csr, diag, a0, a0, hi1, s16, lsh, n, 0);
        // Tx2 = 2*prop(Tx1) - Tx0 -> hi2
        k_gather<<<gGat, blk, 0, stream>>>(rowst, cntd, csr, diag, hi1, a0, hi2, s16, lsh, n, 1);
        // out = relu([Tx0|Tx1|Tx2] @ W + b)
        k_gemm16<<<gGemm, blk, 0, stream>>>(a0, hi1, hi2, s16, ksteps, wt[l], bl[l],
                                            (l == 3) ? H : nullptr,
                                            (l < 3) ? hi0 : nullptr, n);
    }

    // --- fused pool + FC head (no atomics; batch is sorted) ---
    k_pool_fc<<<NG, blk, 0, stream>>>(H, gstart, fcw, fcb, out);
}

// Round 11
// 814.555 us; speedup vs baseline: 2.2324x; 1.0453x over previous
//
#include <hip/hip_runtime.h>
#include <math.h>

#define NN 50000
#define MP 50048          // NN padded to multiple of 128 (32 rows x 4 waves)
#define NE 800000
#define FIN 64
#define HD 200
#define NG 256
#define SCAN_B 256
#define KPAD 224          // HD padded to multiple of 32 for MFMA K-steps
#define NT 13             // 13 * 16 = 208 >= 200 output col tiles
#define HB 12544          // LDS histogram packed dwords (covers 25088 nodes/pass)
#define PER_B 3125        // NE / 256 edges per histogram block

typedef _Float16 h16;
typedef __attribute__((ext_vector_type(8))) _Float16 half8;
typedef __attribute__((ext_vector_type(4))) float float4v;
typedef unsigned long long u64;

// ---------- histogram: per-block LDS counts (u16-packed, 2 node-range passes) ----------
__global__ __launch_bounds__(256) void k_hist(const int* __restrict__ idx,
                                              unsigned* __restrict__ partial, int E) {
    __shared__ unsigned h[HB];
    int tid = threadIdx.x;
    int e0 = blockIdx.x * PER_B;
    int v[13];
#pragma unroll
    for (int j = 0; j < 13; ++j) {
        int o = j * 256 + tid;
        v[j] = (o < PER_B) ? idx[e0 + o] : -1;
    }
#pragma unroll
    for (int pass = 0; pass < 2; ++pass) {
        for (int t = tid; t < HB; t += 256) h[t] = 0;
        __syncthreads();
        int lo = pass * (2 * HB);
#pragma unroll
        for (int j = 0; j < 13; ++j) {
            int vv = v[j] - lo;
            if (vv >= 0 && vv < 2 * HB)
                atomicAdd(&h[vv >> 1], (vv & 1) ? 0x10000u : 1u);
        }
        __syncthreads();
        unsigned* pb = partial + ((size_t)pass * 256 + blockIdx.x) * HB;
        for (int t = tid; t < HB; t += 256) pb[t] = h[t];
        __syncthreads();
    }
}

// sum 256 per-block partials -> int counts (both packed halves)
__global__ void k_hreduce(const unsigned* __restrict__ partial, int* __restrict__ cnt, int n) {
    int i = blockIdx.x * blockDim.x + threadIdx.x;
    if (i >= 2 * HB) return;
    int pass = i / HB, p = i - pass * HB;
    const unsigned* pb = partial + (size_t)pass * 256 * HB + p;
    unsigned s = 0;
    for (int b = 0; b < 256; ++b) s += pb[(size_t)b * HB];
    int n0 = pass * 2 * HB + 2 * p;
    if (n0 < n)     cnt[n0]     = (int)(s & 0xffffu);
    if (n0 + 1 < n) cnt[n0 + 1] = (int)(s >> 16);
}

// in-place: partial[pass][b][p] -> exclusive prefix over b (u16-packed); totals -> cnt
// (per-half cumulative <= in-degree <= ~45, no cross-half carry)
__global__ void k_hscan(unsigned* __restrict__ partial, int* __restrict__ cnt, int n) {
    int i = blockIdx.x * blockDim.x + threadIdx.x;
    if (i >= 2 * HB) return;
    int pass = i / HB, p = i - pass * HB;
    unsigned* pb = partial + (size_t)pass * 256 * HB + p;
    unsigned run = 0;
    for (int b = 0; b < 256; ++b) {
        unsigned c = pb[(size_t)b * HB];
        pb[(size_t)b * HB] = run;
        run += c;
    }
    int n0 = pass * 2 * HB + 2 * p;
    if (n0 < n)     cnt[n0]     = (int)(run & 0xffffu);
    if (n0 + 1 < n) cnt[n0 + 1] = (int)(run >> 16);
}

// dis[i]=deg^-1/2 ; qs[i]=-dis[i]*2/lmax[batch[i]] (src-side weight factor); diag
__global__ void k_node_prep(const int* __restrict__ degi, const int* __restrict__ batch,
                            const float* __restrict__ lmax, float* __restrict__ dis,
                            float* __restrict__ qs, float* __restrict__ diag, int n) {
    int i = blockIdx.x * blockDim.x + threadIdx.x;
    if (i < n) {
        int d = degi[i];
        float di = (d > 0) ? (1.0f / sqrtf((float)d)) : 0.0f;
        float sc = 2.0f / lmax[batch[i]];
        dis[i] = di;
        qs[i] = -di * sc;
        diag[i] = sc - 1.0f;
    }
}

// ---------- exclusive scan over cnt_dst ----------
__global__ void k_scan1(const int* __restrict__ cnt, int* __restrict__ excl,
                        int* __restrict__ bsum, int n) {
    __shared__ int sh[SCAN_B];
    int tid = threadIdx.x;
    int i = blockIdx.x * SCAN_B + tid;
    int v = (i < n) ? cnt[i] : 0;
    sh[tid] = v;
    __syncthreads();
    for (int off = 1; off < SCAN_B; off <<= 1) {
        int t = (tid >= off) ? sh[tid - off] : 0;
        __syncthreads();
        sh[tid] += t;
        __syncthreads();
    }
    if (i < n) excl[i] = sh[tid] - v;
    if (tid == SCAN_B - 1) bsum[blockIdx.x] = sh[tid];
}

__global__ void k_scan2(int* __restrict__ bsum, int nb) {
    __shared__ int sh[SCAN_B];
    int tid = threadIdx.x;
    int v = (tid < nb) ? bsum[tid] : 0;
    sh[tid] = v;
    __syncthreads();
    for (int off = 1; off < SCAN_B; off <<= 1) {
        int t = (tid >= off) ? sh[tid - off] : 0;
        __syncthreads();
        sh[tid] += t;
        __syncthreads();
    }
    if (tid < nb) bsum[tid] = sh[tid] - v;   // exclusive
}

__global__ void k_scan3(int* __restrict__ excl, const int* __restrict__ bsum, int n) {
    int i = blockIdx.x * SCAN_B + threadIdx.x;
    if (i < n) excl[i] += bsum[blockIdx.x];
}

// ---------- CSR fill, ZERO global atomics ----------
// pos = rowst[d] + hpart_exclusive[pass][block][d] + LDS-local rank
// (same block/edge partition as k_hist(dst) -> bases are consistent)
__global__ __launch_bounds__(256) void k_fillcsr2(
    const int* __restrict__ src, const int* __restrict__ dst,
    const float* __restrict__ qs, const float* __restrict__ dis,
    const int* __restrict__ rowst, const unsigned* __restrict__ hpart,
    u64* __restrict__ csr, int E) {
    __shared__ unsigned lrank[HB];
    int tid = threadIdx.x;
    int e0 = blockIdx.x * PER_B;
    int vs[13], vd[13];
#pragma unroll
    for (int j = 0; j < 13; ++j) {
        int o = j * 256 + tid;
        vs[j] = (o < PER_B) ? src[e0 + o] : -1;
        vd[j] = (o < PER_B) ? dst[e0 + o] : -1;
    }
#pragma unroll
    for (int pass = 0; pass < 2; ++pass) {
        for (int t = tid; t < HB; t += 256) lrank[t] = 0;
        __syncthreads();
        int lo = pass * (2 * HB);
        const unsigned* base = hpart + ((size_t)pass * 256 + blockIdx.x) * HB;
#pragma unroll
        for (int j = 0; j < 13; ++j) {
            int vv = vd[j] - lo;
            if (vv >= 0 && vv < 2 * HB) {
                unsigned old = atomicAdd(&lrank[vv >> 1], (vv & 1) ? 0x10000u : 1u);
                unsigned rank = (vv & 1) ? (old >> 16) : (old & 0xffffu);
                unsigned bs = base[vv >> 1];
                unsigned b = (vv & 1) ? (bs >> 16) : (bs & 0xffffu);
                int s = vs[j], d = vd[j];
                int pos = rowst[d] + (int)b + (int)rank;
                float w = qs[s] * dis[d];
                csr[pos] = (unsigned)s | ((u64)__float_as_uint(w) << 32);
            }
        }
        __syncthreads();
    }
}

// ---------- fp32 -> fp16 split for x ----------
__global__ void k_split(const float* __restrict__ x, h16* __restrict__ x16, int total) {
    int i = blockIdx.x * blockDim.x + threadIdx.x;
    if (i < total) x16[i] = (h16)x[i];
}

// ---------- W pre-transpose: f32 [3][fin][HD] -> fp16 [seg][ks][208][32] ----------
__global__ void k_wprep(const float* __restrict__ W, h16* __restrict__ out,
                        int fin, int ksteps, int total) {
    int idx = blockIdx.x * blockDim.x + threadIdx.x;
    if (idx >= total) return;
    int kk = idx & 31;
    int r = idx >> 5;
    int nn = r % 208;
    int r2 = r / 208;
    int ks = r2 % ksteps;
    int seg = r2 / ksteps;
    int k = ks * 32 + kk;
    out[idx] = (nn < HD && k < fin) ? (h16)W[((size_t)seg * fin + k) * HD + nn] : (h16)0.f;
}

// ---------- graph boundaries (batch is sorted) ----------
__global__ void k_bounds(const int* __restrict__ batch, int* __restrict__ gstart, int n) {
    int g = blockIdx.x * blockDim.x + threadIdx.x;
    if (g > NG) return;
    if (g == NG) { gstart[NG] = n; return; }
    int lo = 0, hi = n;
    while (lo < hi) {
        int mid = (lo + hi) >> 1;
        if (batch[mid] < g) lo = mid + 1; else hi = mid;
    }
    gstart[g] = lo;
}

// ---------- propagation (gather, fp16, latency-optimized 8-edge pipeline) ----------
// One lane-group per node: group = 2^lsh lanes (64 for s16=224, 16 for s16=64).
// mode 0: v = gath + diag*hin        mode 1: v = 2*(gath + diag*hin) - hin0
__global__ __launch_bounds__(256) void k_gather(
    const int* __restrict__ rowstart, const int* __restrict__ rowcnt,
    const u64* __restrict__ csr, const float* __restrict__ diag,
    const h16* __restrict__ hin16, const h16* __restrict__ h016,
    h16* __restrict__ hout16, int s16, int lsh, int n, int mode) {
    int per = 256 >> lsh;
    int i = blockIdx.x * per + (threadIdx.x >> lsh);
    if (i >= n) return;
    int lane = threadIdx.x & ((1 << lsh) - 1);
    int c0 = lane * 4;
    if (c0 >= s16) return;
    int start = rowstart[i], cnt = rowcnt[i];
    float a0 = 0.f, a1 = 0.f, a2 = 0.f, a3 = 0.f;
    union U { uint2 u; h16 h[4]; };
    const u64* cp = csr + start;
    int k = 0;
    for (; k + 7 < cnt; k += 8) {
        u64 e[8];
#pragma unroll
        for (int j = 0; j < 8; ++j) e[j] = cp[k + j];           // broadcast, independent
        U p[8];
#pragma unroll
        for (int j = 0; j < 8; ++j)                              // 8 rows in flight
            p[j].u = *(const uint2*)(hin16 + (size_t)(unsigned)(e[j] & 0xffffffffu) * s16 + c0);
#pragma unroll
        for (int j = 0; j < 8; ++j) {
            float w = __uint_as_float((unsigned)(e[j] >> 32));
            a0 += w * (float)p[j].h[0];
            a1 += w * (float)p[j].h[1];
            a2 += w * (float)p[j].h[2];
            a3 += w * (float)p[j].h[3];
        }
    }
    for (; k + 1 < cnt; k += 2) {
        u64 e0 = cp[k], e1 = cp[k + 1];
        U p0, p1;
        p0.u = *(const uint2*)(hin16 + (size_t)(unsigned)(e0 & 0xffffffffu) * s16 + c0);
        p1.u = *(const uint2*)(hin16 + (size_t)(unsigned)(e1 & 0xffffffffu) * s16 + c0);
        float w0 = __uint_as_float((unsigned)(e0 >> 32));
        float w1 = __uint_as_float((unsigned)(e1 >> 32));
        a0 += w0 * (float)p0.h[0] + w1 * (float)p1.h[0];
        a1 += w0 * (float)p0.h[1] + w1 * (float)p1.h[1];
        a2 += w0 * (float)p0.h[2] + w1 * (float)p1.h[2];
        a3 += w0 * (float)p0.h[3] + w1 * (float)p1.h[3];
    }
    if (k < cnt) {
        u64 e0 = cp[k];
        U p0;
        p0.u = *(const uint2*)(hin16 + (size_t)(unsigned)(e0 & 0xffffffffu) * s16 + c0);
        float w0 = __uint_as_float((unsigned)(e0 >> 32));
        a0 += w0 * (float)p0.h[0];
        a1 += w0 * (float)p0.h[1];
        a2 += w0 * (float)p0.h[2];
        a3 += w0 * (float)p0.h[3];
    }
    float dg = diag[i];
    U hs; hs.u = *(const uint2*)(hin16 + (size_t)i * s16 + c0);
    float v0 = a0 + dg * (float)hs.h[0];
    float v1 = a1 + dg * (float)hs.h[1];
    float v2 = a2 + dg * (float)hs.h[2];
    float v3 = a3 + dg * (float)hs.h[3];
    if (mode == 1) {
        U h0; h0.u = *(const uint2*)(h016 + (size_t)i * s16 + c0);
        v0 = 2.f * v0 - (float)h0.h[0];
        v1 = 2.f * v1 - (float)h0.h[1];
        v2 = 2.f * v2 - (float)h0.h[2];
        v3 = 2.f * v3 - (float)h0.h[3];
    }
    U o;
    o.h[0] = (h16)v0; o.h[1] = (h16)v1; o.h[2] = (h16)v2; o.h[3] = (h16)v3;
    *(uint2*)(hout16 + (size_t)i * s16 + c0) = o.u;
}

// ---------- MFMA fp16 GEMM, barrier-free: out = relu([A0|A1|A2] @ W + b) ----------
// Each wave: 32 rows x 208 cols. In-place out16 over an A-buffer is safe:
// each row is read only by the wave that writes it, reads precede epilogue.
__global__ __launch_bounds__(256) void k_gemm16(
    const h16* __restrict__ A0, const h16* __restrict__ A1, const h16* __restrict__ A2,
    int strideA, int ksteps,
    const h16* __restrict__ Wt, const float* __restrict__ bias,
    h16* __restrict__ out16, int n) {
    int tid = threadIdx.x;
    int wave = tid >> 6, lane = tid & 63;
    int nq = lane & 15, quad = lane >> 4;
    int row0 = (blockIdx.x * 4 + wave) * 32;
    const h16* Aseg[3] = {A0, A1, A2};

    float4v acc[2][NT];
#pragma unroll
    for (int r = 0; r < 2; r++)
#pragma unroll
        for (int t = 0; t < NT; t++) acc[r][t] = (float4v)0.f;

    for (int seg = 0; seg < 3; ++seg) {
        const h16* Ab = Aseg[seg] + (size_t)(row0 + nq) * strideA + quad * 8;
        const h16* Bb = Wt + (size_t)seg * ksteps * 208 * 32 + (size_t)nq * 32 + quad * 8;
        for (int ks = 0; ks < ksteps; ++ks) {
            half8 af0 = *(const half8*)(Ab + ks * 32);
            half8 af1 = *(const half8*)(Ab + 16 * strideA + ks * 32);
            const h16* Bk = Bb + (size_t)ks * 208 * 32;
#pragma unroll
            for (int t = 0; t < NT; ++t) {
                half8 bf = *(const half8*)(Bk + t * 16 * 32);
                acc[0][t] = __builtin_amdgcn_mfma_f32_16x16x32_f16(af0, bf, acc[0][t], 0, 0, 0);
                acc[1][t] = __builtin_amdgcn_mfma_f32_16x16x32_f16(af1, bf, acc[1][t], 0, 0, 0);
            }
        }
    }
#pragma unroll
    for (int r = 0; r < 2; ++r) {
        int rowb = row0 + r * 16 + quad * 4;
#pragma unroll
        for (int t = 0; t < NT; ++t) {
            int col = t * 16 + nq;
            if (col >= HD) continue;
            float bj = bias[col];
#pragma unroll
            for (int g = 0; g < 4; ++g) {
                int row = rowb + g;
                if (row < n)
                    out16[(size_t)row * KPAD + col] = (h16)fmaxf(acc[r][t][g] + bj, 0.0f);
            }
        }
    }
}

// ---------- fused segmented pool (mean+max) + FC + log_softmax (fp16 input) ----------
__global__ __launch_bounds__(256) void k_pool_fc(
    const h16* __restrict__ Hf, const int* __restrict__ gstart,
    const float* __restrict__ fcw, const float* __restrict__ fcb,
    float* __restrict__ out) {
    __shared__ float red[8];
    int g = blockIdx.x;
    int j = threadIdx.x;
    int i0 = gstart[g], i1 = gstart[g + 1];
    float s0 = 0.f, s1 = 0.f, s2 = 0.f, s3 = 0.f, mx = 0.f;   // post-ReLU: max >= 0
    if (j < HD) {
        int i = i0;
        for (; i + 3 < i1; i += 4) {
            float v0 = (float)Hf[(size_t)i * KPAD + j];
            float v1 = (float)Hf[(size_t)(i + 1) * KPAD + j];
            float v2 = (float)Hf[(size_t)(i + 2) * KPAD + j];
            float v3 = (float)Hf[(size_t)(i + 3) * KPAD + j];
            s0 += v0; s1 += v1; s2 += v2; s3 += v3;
            mx = fmaxf(mx, fmaxf(fmaxf(v0, v1), fmaxf(v2, v3)));
        }
        for (; i < i1; ++i) {
            float v = (float)Hf[(size_t)i * KPAD + j];
            s0 += v; mx = fmaxf(mx, v);
        }
    }
    float cntf = (float)(i1 - i0);
    float mean = (s0 + s1 + s2 + s3) / fmaxf(cntf, 1.f);
    float p0 = 0.f, p1 = 0.f;
    if (j < HD) {
        p0 = mean * fcw[2 * j]     + mx * fcw[2 * (HD + j)];
        p1 = mean * fcw[2 * j + 1] + mx * fcw[2 * (HD + j) + 1];
    }
#pragma unroll
    for (int o = 32; o > 0; o >>= 1) {
        p0 += __shfl_down(p0, o);
        p1 += __shfl_down(p1, o);
    }
    int wave = j >> 6, lane = j & 63;
    if (lane == 0) { red[wave * 2] = p0; red[wave * 2 + 1] = p1; }
    __syncthreads();
    if (j == 0) {
        float z0 = red[0] + red[2] + red[4] + red[6] + fcb[0];
        float z1 = red[1] + red[3] + red[5] + red[7] + fcb[1];
        float m = fmaxf(z0, z1);
        float lse = m + logf(expf(z0 - m) + expf(z1 - m));
        out[g * 2 + 0] = z0 - lse;
        out[g * 2 + 1] = z1 - lse;
    }
}

extern "C" void kernel_launch(void* const* d_in, const int* in_sizes, int n_in,
                              void* d_out, int out_size, void* d_ws, size_t ws_size,
                              hipStream_t stream) {
    const float* x     = (const float*)d_in[0];
    const int*   edge  = (const int*)d_in[1];
    const int*   batch = (const int*)d_in[2];
    const float* lmax  = (const float*)d_in[3];
    const float* W1 = (const float*)d_in[4];  const float* b1 = (const float*)d_in[5];
    const float* W2 = (const float*)d_in[6];  const float* b2 = (const float*)d_in[7];
    const float* W3 = (const float*)d_in[8];  const float* b3 = (const float*)d_in[9];
    const float* W4 = (const float*)d_in[10]; const float* b4 = (const float*)d_in[11];
    const float* fcw = (const float*)d_in[12]; const float* fcb = (const float*)d_in[13];
    float* out = (float*)d_out;

    const int n = NN, E = NE;
    const int* src = edge;
    const int* dst = edge + E;

    // workspace layout (float units, each buffer 16B-aligned)
    float* ws = (float*)d_ws;
    size_t off = 0;
    auto alloc = [&](size_t nfloats) { float* p = ws + off; off += (nfloats + 3) & ~(size_t)3; return p; };
    int*   degi   = (int*)alloc(NN);
    float* dis    = alloc(NN);
    float* qs     = alloc(NN);
    float* diag   = alloc(NN);
    int*   cntd   = (int*)alloc(NN);
    int*   rowst  = (int*)alloc(NN);
    int*   bsum   = (int*)alloc(SCAN_B);
    u64*   csr    = (u64*)alloc((size_t)NE * 2);          // packed {src, w}
    int*   gstart = (int*)alloc(NG + 1);
    unsigned* hpart = (unsigned*)alloc((size_t)2 * 256 * HB);  // histogram partials (25.7 MB)
    h16*   x16    = (h16*)alloc((size_t)MP * FIN / 2);    // fp16 x (stride 64)
    h16*   hi0    = (h16*)alloc((size_t)MP * KPAD / 2);   // fp16 Tx0 (in-place per layer)
    h16*   hi1    = (h16*)alloc((size_t)MP * KPAD / 2);   // fp16 Tx1 / final pool buffer
    h16*   hi2    = (h16*)alloc((size_t)MP * KPAD / 2);   // fp16 Tx2
    const int WSZ0 = 3 * 2 * 208 * 32;                    // layer 0 (fin=64, ksteps=2)
    const int WSZ  = 3 * 7 * 208 * 32;                    // layers 1-3 (fin=200, ksteps=7)
    h16* wt0 = (h16*)alloc(WSZ0 / 2);
    h16* wt1 = (h16*)alloc(WSZ / 2);
    h16* wt2 = (h16*)alloc(WSZ / 2);
    h16* wt3 = (h16*)alloc(WSZ / 2);

    dim3 blk(256);
    int gE = (E + 255) / 256;
    int gN = (n + 255) / 256;
    int gScan = (n + SCAN_B - 1) / SCAN_B;
    int gGemm = MP / 128;         // 391 blocks, 4 waves x 32 rows
    int gHR = (2 * HB + 255) / 256;

    // --- W pre-transpose (L2-resident fp16 fragments) + x fp16 + bounds ---
    k_wprep<<<(WSZ0 + 255) / 256, blk, 0, stream>>>(W1, wt0, FIN, 2, WSZ0);
    k_wprep<<<(WSZ + 255) / 256, blk, 0, stream>>>(W2, wt1, HD, 7, WSZ);
    k_wprep<<<(WSZ + 255) / 256, blk, 0, stream>>>(W3, wt2, HD, 7, WSZ);
    k_wprep<<<(WSZ + 255) / 256, blk, 0, stream>>>(W4, wt3, HD, 7, WSZ);
    k_split<<<(NN * FIN + 255) / 256, blk, 0, stream>>>(x, x16, NN * FIN);
    k_bounds<<<2, blk, 0, stream>>>(batch, gstart, n);
    // hi0 pads (cols 200..223 + tail rows) must be zero: gemm only writes cols<200
    hipMemsetAsync(hi0, 0, (size_t)MP * KPAD * 2, stream);

    // --- degrees + CSR bases via LDS histograms (no global atomics anywhere) ---
    k_hist<<<256, blk, 0, stream>>>(src, hpart, E);
    k_hreduce<<<gHR, blk, 0, stream>>>(hpart, degi, n);
    k_hist<<<256, blk, 0, stream>>>(dst, hpart, E);
    k_hscan<<<gHR, blk, 0, stream>>>(hpart, cntd, n);     // cntd + per-block bases
    k_node_prep<<<gN, blk, 0, stream>>>(degi, batch, lmax, dis, qs, diag, n);

    // --- CSR build (atomic-free) ---
    k_scan1<<<gScan, blk, 0, stream>>>(cntd, rowst, bsum, n);
    k_scan2<<<1, blk, 0, stream>>>(bsum, gScan);
    k_scan3<<<gScan, blk, 0, stream>>>(rowst, bsum, n);
    k_fillcsr2<<<256, blk, 0, stream>>>(src, dst, qs, dis, rowst, hpart, csr, E);

    // --- 4 Chebyshev layers ---
    const h16* wt[4] = {wt0, wt1, wt2, wt3};
    const float* bl[4] = {b1, b2, b3, b4};
    for (int l = 0; l < 4; l++) {
        int s16 = (l == 0) ? FIN : KPAD;
        int lsh = (l == 0) ? 4 : 6;                  // 16-lane groups (l0) / full wave
        int per = 256 >> lsh;
        int gGat = (n + per - 1) / per;
        int ksteps = (l == 0) ? 2 : 7;
        const h16* a0 = (l == 0) ? x16 : hi0;
        // Tx1 = prop(Tx0) -> hi1
        k_gather<<<gGat, blk, 0, stream>>>(rowst, cntd, csr, diag, a0, a0, hi1, s16, lsh, n, 0);
        // Tx2 = 2*prop(Tx1) - Tx0 -> hi2
        k_gather<<<gGat, blk, 0, stream>>>(rowst, cntd, csr, diag, hi1, a0, hi2, s16, lsh, n, 1);
        // out = relu([Tx0|Tx1|Tx2] @ W + b) -> hi0 (layers 0-2) or hi1 (final, pool input)
        k_gemm16<<<gGemm, blk, 0, stream>>>(a0, hi1, hi2, s16, ksteps, wt[l], bl[l],
                                            (l < 3) ? hi0 : hi1, n);
    }

    // --- fused pool + FC head (no atomics; batch is sorted; fp16 input) ---
    k_pool_fc<<<NG, blk, 0, stream>>>(hi1, gstart, fcw, fcb, out);
}